// Round 8
// baseline (16.646 us; speedup 1.0000x reference)
//
#include <hip/hip_runtime.h>

namespace {

constexpr int NO  = 256;
constexpr int NK  = 32;
constexpr int NI  = 512;
constexpr int BLK = 1024;              // 16 waves
constexpr int NB  = (NO * NK) / BLK;   // 8 blocks
constexpr int OWIN = BLK / NK;         // 32 o-values per block

using u32 = unsigned int;
using u64 = unsigned long long;

// Inputs/outputs are float32 (established rounds 1-2: bf16 interpretation
// NaN'd, runtime detector chose f32, npz compression = 3.6 B/elem).
__global__ __launch_bounds__(BLK) void gm_fused_kernel(
    const float* __restrict__ weights,   // (512)
    const float* __restrict__ means,     // (512,3)
    const float* __restrict__ covars,    // (512,3,3)
    const float* __restrict__ k_weights, // (256,32)
    const float* __restrict__ k_means,   // (256,32,3)
    const float* __restrict__ k_scales,  // (256,32,3)
    const float* __restrict__ k_quats,   // (256,32,4)
    float* __restrict__ out)             // [W 8192][mu 24576][cov 73728]
{
  // 64-bit sort key: (w_bits<<32) | (511-i). Weights strictly positive so
  // IEEE f32 bits compare like the floats; low word reproduces
  // jax.lax.top_k's stable-descending tie rule (tie -> lower index first).
  __shared__ __align__(16) u64 keys[NI];
  __shared__ float sm[NI * 3];           // means stash (anchor source)
  __shared__ float anchors[OWIN * 3];    // this block's 32 anchors
  __shared__ float red[16][6];           // per-wave moment partials
  __shared__ float stats[10];            // S, Σwm[3], Σw(c+mmᵀ)[6] raw sums

  const int tid   = threadIdx.x;         // 0..1023
  const int lane  = tid & 63;
  const int wave  = tid >> 6;
  const bool lower = tid < NI;
  const int item  = lower ? tid : tid - NI;
  const int b     = blockIdx.x;

  // ---- prefetch emit inputs ----
  const int t = b * BLK + tid;           // 0..8191 == o*32+k
  const float  kw  = k_weights[t];
  const float  km0 = k_means[3 * t + 0];
  const float  km1 = k_means[3 * t + 1];
  const float  km2 = k_means[3 * t + 2];
  const float4 q4  = *(const float4*)(k_quats + 4 * t);   // 16B-aligned
  const float  s0  = k_scales[3 * t + 0];
  const float  s1  = k_scales[3 * t + 1];
  const float  s2  = k_scales[3 * t + 2];

  // ---- phase A: split moment accumulation across the two thread halves ----
  const float w  = weights[item];
  const float m0 = means[3 * item + 0];
  const float m1 = means[3 * item + 1];
  const float m2 = means[3 * item + 2];

  float acc[6] = {0.f, 0.f, 0.f, 0.f, 0.f, 0.f};
  if (lower) {
    acc[0] = w;
    acc[1] = w * m0; acc[2] = w * m1; acc[3] = w * m2;
    keys[item] = ((u64)__float_as_uint(w) << 32) | (u32)(NI - 1 - item);
    sm[3 * item + 0] = m0; sm[3 * item + 1] = m1; sm[3 * item + 2] = m2;
  } else {
    const float c00 = covars[9 * item + 0];
    const float c01 = covars[9 * item + 1];
    const float c02 = covars[9 * item + 2];
    const float c11 = covars[9 * item + 4];
    const float c12 = covars[9 * item + 5];
    const float c22 = covars[9 * item + 8];
    acc[0] = w * (c00 + m0 * m0);
    acc[1] = w * (c01 + m0 * m1);
    acc[2] = w * (c02 + m0 * m2);
    acc[3] = w * (c11 + m1 * m1);
    acc[4] = w * (c12 + m1 * m2);
    acc[5] = w * (c22 + m2 * m2);
  }

  #pragma unroll
  for (int off = 32; off > 0; off >>= 1) {
    #pragma unroll
    for (int e = 0; e < 6; ++e) acc[e] += __shfl_down(acc[e], off, 64);
  }
  if (lane == 0) {
    #pragma unroll
    for (int e = 0; e < 6; ++e) red[wave][e] = acc[e];
  }

  // ---- quat -> M M^T precompute (hides under load latency / reduce stalls;
  //      depends only on per-thread k_* values) ----
  float Q[9];
  {
    float qw = q4.x, qx = q4.y, qy = q4.z, qz = q4.w;
    const float rn = rsqrtf(qw * qw + qx * qx + qy * qy + qz * qz);
    qw *= rn; qx *= rn; qy *= rn; qz *= rn;

    float R[3][3];
    R[0][0] = 1.f - 2.f * (qy * qy + qz * qz);
    R[0][1] = 2.f * (qx * qy - qw * qz);
    R[0][2] = 2.f * (qx * qz + qw * qy);
    R[1][0] = 2.f * (qx * qy + qw * qz);
    R[1][1] = 1.f - 2.f * (qx * qx + qz * qz);
    R[1][2] = 2.f * (qy * qz - qw * qx);
    R[2][0] = 2.f * (qx * qz - qw * qy);
    R[2][1] = 2.f * (qy * qz + qw * qx);
    R[2][2] = 1.f - 2.f * (qx * qx + qy * qy);

    const float sc[3] = { s0, s1, s2 };
    float M[3][3];
    #pragma unroll
    for (int rr = 0; rr < 3; ++rr)
      #pragma unroll
      for (int cc = 0; cc < 3; ++cc)
        M[rr][cc] = R[rr][cc] * sc[cc];

    #pragma unroll
    for (int rr = 0; rr < 3; ++rr)
      #pragma unroll
      for (int cc = 0; cc < 3; ++cc) {
        float a = 0.f;
        #pragma unroll
        for (int e = 0; e < 3; ++e) a += M[rr][e] * M[cc][e];
        Q[3 * rr + cc] = a;
      }
  }

  __syncthreads();                       // keys, sm, red visible

  // parallel moment combine (done by wave 0's first 10 lanes)
  if (tid < 10) {
    float s = 0.f;
    if (tid < 4) {
      #pragma unroll
      for (int wv = 0; wv < 8; ++wv) s += red[wv][tid];
    } else {
      #pragma unroll
      for (int wv = 8; wv < 16; ++wv) s += red[wv][tid - 4];
    }
    stats[tid] = s;
  }

  // ---- rank scan: item p = tid>>1 scanned by adjacent lanes (2p, 2p+1),
  //      each over a disjoint half; combine via one shfl_xor (no barrier). ----
  const int  pair  = tid >> 1;
  const u64  mykey = keys[pair];
  const ulonglong2* seg = (const ulonglong2*)(keys + (tid & 1) * (NI / 2));
  int r0 = 0, r1 = 0, r2 = 0, r3 = 0, r4 = 0, r5 = 0, r6 = 0, r7 = 0;
  #pragma unroll 4
  for (int p = 0; p < 32; ++p) {         // 32 iters, 8 keys each
    const ulonglong2 ka = seg[4 * p + 0];
    const ulonglong2 kb = seg[4 * p + 1];
    const ulonglong2 kc = seg[4 * p + 2];
    const ulonglong2 kd = seg[4 * p + 3];
    r0 += (int)(ka.x > mykey);
    r1 += (int)(ka.y > mykey);
    r2 += (int)(kb.x > mykey);
    r3 += (int)(kb.y > mykey);
    r4 += (int)(kc.x > mykey);
    r5 += (int)(kc.y > mykey);
    r6 += (int)(kd.x > mykey);
    r7 += (int)(kd.y > mykey);
  }
  int r = ((r0 + r1) + (r2 + r3)) + ((r4 + r5) + (r6 + r7));
  const int rank = r + __shfl_xor(r, 1, 64);

  // this block only needs anchors for ranks in [OWIN*b, OWIN*b+OWIN)
  if ((tid & 1) == 0) {
    const int lr = rank - OWIN * b;
    if ((unsigned)lr < (unsigned)OWIN) {
      anchors[3 * lr + 0] = sm[3 * pair + 0];
      anchors[3 * lr + 1] = sm[3 * pair + 1];
      anchors[3 * lr + 2] = sm[3 * pair + 2];
    }
  }
  __syncthreads();                       // anchors + stats visible

  // ---- emit: merged stats + precomputed Q, 1 output per thread ----
  const float S   = stats[0];
  const float inv = 1.f / S;
  const float b0 = stats[1] * inv, b1 = stats[2] * inv, b2 = stats[3] * inv;
  const float C00 = stats[4] * inv - b0 * b0;
  const float C01 = stats[5] * inv - b0 * b1;
  const float C02 = stats[6] * inv - b0 * b2;
  const float C11 = stats[7] * inv - b1 * b1;
  const float C12 = stats[8] * inv - b1 * b2;
  const float C22 = stats[9] * inv - b2 * b2;

  const int ol = tid >> 5;               // local o index 0..31
  const float a0 = anchors[3 * ol + 0];
  const float a1 = anchors[3 * ol + 1];
  const float a2 = anchors[3 * ol + 2];

  out[t] = kw * S;
  const int mu_base = NO * NK + 3 * t;
  out[mu_base + 0] = a0 + km0 + b0;
  out[mu_base + 1] = a1 + km1 + b1;
  out[mu_base + 2] = a2 + km2 + b2;

  const float Cb[9] = { C00, C01, C02, C01, C11, C12, C02, C12, C22 };
  const int cov_base = NO * NK * 4 + 9 * t;
  #pragma unroll
  for (int e = 0; e < 9; ++e)
    out[cov_base + e] = Q[e] + Cb[e];
}

} // anonymous namespace

extern "C" void kernel_launch(void* const* d_in, const int* in_sizes, int n_in,
                              void* d_out, int out_size, void* d_ws, size_t ws_size,
                              hipStream_t stream) {
  const float* weights   = (const float*)d_in[0];
  const float* means     = (const float*)d_in[1];
  const float* covars    = (const float*)d_in[2];
  // d_in[3] = features — unused by the reference
  const float* k_weights = (const float*)d_in[4];
  const float* k_means   = (const float*)d_in[5];
  const float* k_scales  = (const float*)d_in[6];
  const float* k_quats   = (const float*)d_in[7];

  gm_fused_kernel<<<NB, BLK, 0, stream>>>(weights, means, covars,
                                          k_weights, k_means, k_scales, k_quats,
                                          (float*)d_out);
}

// Round 9
// 14.232 us; speedup vs baseline: 1.1697x; 1.1697x over previous
//
#include <hip/hip_runtime.h>

namespace {

constexpr int NO  = 256;
constexpr int NK  = 32;
constexpr int NI  = 512;
constexpr int BLK = 1024;              // 16 waves
constexpr int NB  = (NO * NK) / BLK;   // 8 blocks

using u32 = unsigned int;
using u64 = unsigned long long;

// Inputs/outputs are float32 (established rounds 1-2: bf16 interpretation
// NaN'd, runtime detector chose f32, npz compression = 3.6 B/elem).
// Best measured structure (rounds 5/7: 14.24/14.31 us). Scan is wave-uniform
// broadcast (all lanes of a wave read the same key addresses); Q math stays
// in the emit phase to keep the live set across the scan minimal.
__global__ __launch_bounds__(BLK) void gm_fused_kernel(
    const float* __restrict__ weights,   // (512)
    const float* __restrict__ means,     // (512,3)
    const float* __restrict__ covars,    // (512,3,3)
    const float* __restrict__ k_weights, // (256,32)
    const float* __restrict__ k_means,   // (256,32,3)
    const float* __restrict__ k_scales,  // (256,32,3)
    const float* __restrict__ k_quats,   // (256,32,4)
    float* __restrict__ out)             // [W 8192][mu 24576][cov 73728]
{
  // 64-bit sort key: (w_bits<<32) | (511-i). Weights strictly positive so
  // IEEE f32 bits compare like the floats; the low word reproduces
  // jax.lax.top_k's stable-descending tie rule (tie -> lower index first).
  __shared__ __align__(16) u64 keys[NI];
  __shared__ int   rhi[NI];              // rank partial from upper j-half
  __shared__ float anchors[NO * 3];      // top-k means by rank
  __shared__ float red[16][6];           // per-wave moment partials
  __shared__ float stats[10];            // S, Σwm[3], Σw(c+mmᵀ)[6] raw sums

  const int tid   = threadIdx.x;         // 0..1023
  const int lane  = tid & 63;
  const int wave  = tid >> 6;
  const bool lower = tid < NI;
  const int item  = lower ? tid : tid - NI;

  // ---- prefetch emit inputs (latency hides under reduce + rank scan) ----
  const int t = blockIdx.x * BLK + tid;  // 0..8191 == o*32+k
  const int o = t >> 5;
  const float  kw  = k_weights[t];
  const float  km0 = k_means[3 * t + 0];
  const float  km1 = k_means[3 * t + 1];
  const float  km2 = k_means[3 * t + 2];
  const float4 q4  = *(const float4*)(k_quats + 4 * t);   // 16B-aligned
  const float  s0  = k_scales[3 * t + 0];
  const float  s1  = k_scales[3 * t + 1];
  const float  s2  = k_scales[3 * t + 2];

  // ---- phase A: split moment accumulation across the two thread halves ----
  const float w  = weights[item];
  const float m0 = means[3 * item + 0];
  const float m1 = means[3 * item + 1];
  const float m2 = means[3 * item + 2];

  float acc[6] = {0.f, 0.f, 0.f, 0.f, 0.f, 0.f};
  if (lower) {
    acc[0] = w;
    acc[1] = w * m0; acc[2] = w * m1; acc[3] = w * m2;
    keys[item] = ((u64)__float_as_uint(w) << 32) | (u32)(NI - 1 - item);
  } else {
    const float c00 = covars[9 * item + 0];
    const float c01 = covars[9 * item + 1];
    const float c02 = covars[9 * item + 2];
    const float c11 = covars[9 * item + 4];
    const float c12 = covars[9 * item + 5];
    const float c22 = covars[9 * item + 8];
    acc[0] = w * (c00 + m0 * m0);
    acc[1] = w * (c01 + m0 * m1);
    acc[2] = w * (c02 + m0 * m2);
    acc[3] = w * (c11 + m1 * m1);
    acc[4] = w * (c12 + m1 * m2);
    acc[5] = w * (c22 + m2 * m2);
  }

  #pragma unroll
  for (int off = 32; off > 0; off >>= 1) {
    #pragma unroll
    for (int e = 0; e < 6; ++e) acc[e] += __shfl_down(acc[e], off, 64);
  }
  if (lane == 0) {
    #pragma unroll
    for (int e = 0; e < 6; ++e) red[wave][e] = acc[e];
  }
  __syncthreads();                       // keys + red visible

  // parallel moment combine (waves 0-7 hold {S,Σwm}, waves 8-15 covar moments)
  if (tid < 10) {
    float s = 0.f;
    if (tid < 4) {
      #pragma unroll
      for (int wv = 0; wv < 8; ++wv) s += red[wv][tid];
    } else {
      #pragma unroll
      for (int wv = 8; wv < 16; ++wv) s += red[wv][tid - 4];
    }
    stats[tid] = s;
  }

  // ---- rank scan: item i scanned by threads i (lower j-half) and i+512 ----
  const u64 mykey = keys[item];
  const ulonglong2* seg = (const ulonglong2*)(keys + (lower ? 0 : NI / 2));
  int r = 0;
  #pragma unroll 8
  for (int p = 0; p < (NI / 2) / 2; ++p) {   // 128 iters, 2 keys each
    const ulonglong2 kk = seg[p];
    r += (int)(kk.x > mykey);
    r += (int)(kk.y > mykey);
  }
  if (!lower) rhi[item] = r;
  __syncthreads();                       // rhi + stats visible

  if (lower) {
    const int rank = r + rhi[item];
    if (rank < NO) {
      anchors[3 * rank + 0] = m0;
      anchors[3 * rank + 1] = m1;
      anchors[3 * rank + 2] = m2;
    }
  }
  __syncthreads();                       // anchors visible

  // ---- emit: derive merged stats locally, 1 output item per thread ----
  const float S   = stats[0];
  const float inv = 1.f / S;
  const float b0 = stats[1] * inv, b1 = stats[2] * inv, b2 = stats[3] * inv;
  const float C00 = stats[4] * inv - b0 * b0;
  const float C01 = stats[5] * inv - b0 * b1;
  const float C02 = stats[6] * inv - b0 * b2;
  const float C11 = stats[7] * inv - b1 * b1;
  const float C12 = stats[8] * inv - b1 * b2;
  const float C22 = stats[9] * inv - b2 * b2;
  const float a0 = anchors[3 * o + 0];
  const float a1 = anchors[3 * o + 1];
  const float a2 = anchors[3 * o + 2];

  float qw = q4.x, qx = q4.y, qy = q4.z, qz = q4.w;
  const float rn = rsqrtf(qw * qw + qx * qx + qy * qy + qz * qz);
  qw *= rn; qx *= rn; qy *= rn; qz *= rn;

  float R[3][3];
  R[0][0] = 1.f - 2.f * (qy * qy + qz * qz);
  R[0][1] = 2.f * (qx * qy - qw * qz);
  R[0][2] = 2.f * (qx * qz + qw * qy);
  R[1][0] = 2.f * (qx * qy + qw * qz);
  R[1][1] = 1.f - 2.f * (qx * qx + qz * qz);
  R[1][2] = 2.f * (qy * qz - qw * qx);
  R[2][0] = 2.f * (qx * qz - qw * qy);
  R[2][1] = 2.f * (qy * qz + qw * qx);
  R[2][2] = 1.f - 2.f * (qx * qx + qy * qy);

  const float sc[3] = { s0, s1, s2 };
  float M[3][3];
  #pragma unroll
  for (int rr = 0; rr < 3; ++rr)
    #pragma unroll
    for (int cc = 0; cc < 3; ++cc)
      M[rr][cc] = R[rr][cc] * sc[cc];

  const float Cb[9] = { C00, C01, C02, C01, C11, C12, C02, C12, C22 };
  float cov[9];
  #pragma unroll
  for (int rr = 0; rr < 3; ++rr) {
    #pragma unroll
    for (int cc = 0; cc < 3; ++cc) {
      float a = Cb[3 * rr + cc];
      #pragma unroll
      for (int e = 0; e < 3; ++e) a += M[rr][e] * M[cc][e];
      cov[3 * rr + cc] = a;
    }
  }

  out[t] = kw * S;
  const int mu_base = NO * NK + 3 * t;
  out[mu_base + 0] = a0 + km0 + b0;
  out[mu_base + 1] = a1 + km1 + b1;
  out[mu_base + 2] = a2 + km2 + b2;
  const int cov_base = NO * NK * 4 + 9 * t;
  #pragma unroll
  for (int e = 0; e < 9; ++e)
    out[cov_base + e] = cov[e];
}

} // anonymous namespace

extern "C" void kernel_launch(void* const* d_in, const int* in_sizes, int n_in,
                              void* d_out, int out_size, void* d_ws, size_t ws_size,
                              hipStream_t stream) {
  const float* weights   = (const float*)d_in[0];
  const float* means     = (const float*)d_in[1];
  const float* covars    = (const float*)d_in[2];
  // d_in[3] = features — unused by the reference
  const float* k_weights = (const float*)d_in[4];
  const float* k_means   = (const float*)d_in[5];
  const float* k_scales  = (const float*)d_in[6];
  const float* k_quats   = (const float*)d_in[7];

  gm_fused_kernel<<<NB, BLK, 0, stream>>>(weights, means, covars,
                                          k_weights, k_means, k_scales, k_quats,
                                          (float*)d_out);
}